// Round 1
// baseline (906.573 us; speedup 1.0000x reference)
//
#include <hip/hip_runtime.h>
#include <hip/hip_bf16.h>

#define BATCH 4
#define CH 256
#define CRD 32
#define NN 4096
#define QT 64
#define MT 32

// ---------------------------------------------------------------------------
// K1: fused QKV 1x1x1 conv.  q,k: [B][CR][N]  v: stored transposed [B][N][C]
// grid: (ntile=8, otile=10, b=4), block 256.  Each thread owns n and n+256.
// ---------------------------------------------------------------------------
__global__ __launch_bounds__(256) void qkv_kernel(
    const float* __restrict__ x,
    const float* __restrict__ Wq, const float* __restrict__ Wk,
    const float* __restrict__ Wv,
    float* __restrict__ q, float* __restrict__ k, float* __restrict__ v_t)
{
    __shared__ float w_lds[CH][36];   // [c][o] transposed, pad 32->36
    const int t = threadIdx.x;
    const int ntile = blockIdx.x;
    const int otile = blockIdx.y;
    const int b = blockIdx.z;

    const float* W;
    int o_base;
    if (otile == 0)      { W = Wq; o_base = 0; }
    else if (otile == 1) { W = Wk; o_base = 0; }
    else                 { W = Wv; o_base = (otile - 2) * 32; }

    #pragma unroll
    for (int i = 0; i < 32; ++i)
        w_lds[t][i] = W[(o_base + i) * CH + t];
    __syncthreads();

    const int n1 = ntile * 512 + t;
    const int n2 = n1 + 256;
    const float* xb = x + (size_t)b * CH * NN;

    float acc1[32], acc2[32];
    #pragma unroll
    for (int o = 0; o < 32; ++o) { acc1[o] = 0.f; acc2[o] = 0.f; }

    for (int c = 0; c < CH; ++c) {
        float xv1 = xb[c * NN + n1];
        float xv2 = xb[c * NN + n2];
        #pragma unroll
        for (int o = 0; o < 32; ++o) {
            float w = w_lds[c][o];
            acc1[o] += w * xv1;
            acc2[o] += w * xv2;
        }
    }

    if (otile <= 1) {
        float* dst = (otile == 0 ? q : k) + (size_t)b * CRD * NN;
        #pragma unroll
        for (int o = 0; o < 32; ++o) {
            dst[o * NN + n1] = acc1[o];
            dst[o * NN + n2] = acc2[o];
        }
    } else {
        float* dst = v_t + (size_t)b * NN * CH;
        #pragma unroll
        for (int j = 0; j < 8; ++j) {
            *(float4*)&dst[(size_t)n1 * CH + o_base + 4 * j] =
                make_float4(acc1[4*j], acc1[4*j+1], acc1[4*j+2], acc1[4*j+3]);
            *(float4*)&dst[(size_t)n2 * CH + o_base + 4 * j] =
                make_float4(acc2[4*j], acc2[4*j+1], acc2[4*j+2], acc2[4*j+3]);
        }
    }
}

// ---------------------------------------------------------------------------
// K2: flash attention.  grid (N/QT=64, B=4), block 512 (8 waves).
// attn_out written in [B][C][N] layout (normalized softmax @ V).
// ---------------------------------------------------------------------------
__global__ __launch_bounds__(512) void attn_kernel(
    const float* __restrict__ qg, const float* __restrict__ kg,
    const float* __restrict__ vt, float* __restrict__ attn)
{
    __shared__ float q_lds[CRD][QT];       // 8 KB
    __shared__ float k_lds[CRD][MT];       // 4 KB
    __shared__ float v_lds[MT][CH];        // 32 KB
    __shared__ float p_lds[MT][QT + 4];    // 8.5 KB, stride 68 (16B aligned)
    __shared__ float m_state[QT], l_state[QT], alpha_lds[QT];

    const int t = threadIdx.x;
    const int b = blockIdx.y;
    const int qbase = blockIdx.x * QT;
    const float scale = 0.17677669529663687f;   // 1/sqrt(32)

    const float* qb = qg + (size_t)b * CRD * NN + qbase;
    for (int i = t; i < CRD * QT; i += 512) {
        int c = i >> 6, n = i & 63;
        q_lds[c][n] = qb[c * NN + n];
    }
    if (t < QT) { m_state[t] = -1e30f; l_state[t] = 0.f; }

    const int ng = t & 15, cg = t >> 4;          // cg 0..31
    const int n_base = ng * 4, c_base = cg * 8;
    float acc[4][8];
    #pragma unroll
    for (int j = 0; j < 4; ++j)
        #pragma unroll
        for (int cc = 0; cc < 8; ++cc) acc[j][cc] = 0.f;

    __syncthreads();

    const float* kb = kg + (size_t)b * CRD * NN;
    const float* vb = vt + (size_t)b * NN * CH;

    for (int m0 = 0; m0 < NN; m0 += MT) {
        // --- A: stage K and V tiles ---
        for (int i = t; i < CRD * MT; i += 512) {
            int c = i >> 5, m = i & 31;
            k_lds[c][m] = kb[c * NN + m0 + m];
        }
        for (int i = t; i < MT * CH / 4; i += 512) {
            int m = i >> 6, c4 = (i & 63) * 4;
            *(float4*)&v_lds[m][c4] = *(const float4*)&vb[(size_t)(m0 + m) * CH + c4];
        }
        __syncthreads();

        // --- B: score tile s[64n][32m], thread -> 4n x 1m ---
        {
            int sm = t >> 4;   // 0..31
            float s0 = 0.f, s1 = 0.f, s2 = 0.f, s3 = 0.f;
            #pragma unroll
            for (int c = 0; c < CRD; ++c) {
                float kv = k_lds[c][sm];
                float4 q4 = *(float4*)&q_lds[c][n_base];
                s0 += q4.x * kv; s1 += q4.y * kv;
                s2 += q4.z * kv; s3 += q4.w * kv;
            }
            *(float4*)&p_lds[sm][n_base] =
                make_float4(s0 * scale, s1 * scale, s2 * scale, s3 * scale);
        }
        __syncthreads();

        // --- C: online softmax update, 8 threads per query ---
        {
            int qn = t >> 3;   // 0..63
            int mo = t & 7;
            float sv[4];
            float smax = -1e30f;
            #pragma unroll
            for (int j = 0; j < 4; ++j) {
                sv[j] = p_lds[mo + j * 8][qn];
                smax = fmaxf(smax, sv[j]);
            }
            #pragma unroll
            for (int off = 1; off < 8; off <<= 1)
                smax = fmaxf(smax, __shfl_xor(smax, off));
            float mold = m_state[qn];
            float mnew = fmaxf(mold, smax);
            float a = __expf(mold - mnew);
            float psum = 0.f;
            #pragma unroll
            for (int j = 0; j < 4; ++j) {
                float p = __expf(sv[j] - mnew);
                p_lds[mo + j * 8][qn] = p;
                psum += p;
            }
            #pragma unroll
            for (int off = 1; off < 8; off <<= 1)
                psum += __shfl_xor(psum, off);
            if (mo == 0) {
                m_state[qn] = mnew;
                l_state[qn] = l_state[qn] * a + psum;
                alpha_lds[qn] = a;
            }
        }
        __syncthreads();

        // --- D: PV accumulate, thread owns 4n x 8c ---
        {
            float a0 = alpha_lds[n_base + 0];
            float a1 = alpha_lds[n_base + 1];
            float a2 = alpha_lds[n_base + 2];
            float a3 = alpha_lds[n_base + 3];
            #pragma unroll
            for (int cc = 0; cc < 8; ++cc) {
                acc[0][cc] *= a0; acc[1][cc] *= a1;
                acc[2][cc] *= a2; acc[3][cc] *= a3;
            }
            #pragma unroll 4
            for (int m = 0; m < MT; ++m) {
                float4 p4 = *(float4*)&p_lds[m][n_base];
                float4 va = *(float4*)&v_lds[m][c_base];
                float4 vb4 = *(float4*)&v_lds[m][c_base + 4];
                acc[0][0] += p4.x * va.x;  acc[0][1] += p4.x * va.y;
                acc[0][2] += p4.x * va.z;  acc[0][3] += p4.x * va.w;
                acc[0][4] += p4.x * vb4.x; acc[0][5] += p4.x * vb4.y;
                acc[0][6] += p4.x * vb4.z; acc[0][7] += p4.x * vb4.w;
                acc[1][0] += p4.y * va.x;  acc[1][1] += p4.y * va.y;
                acc[1][2] += p4.y * va.z;  acc[1][3] += p4.y * va.w;
                acc[1][4] += p4.y * vb4.x; acc[1][5] += p4.y * vb4.y;
                acc[1][6] += p4.y * vb4.z; acc[1][7] += p4.y * vb4.w;
                acc[2][0] += p4.z * va.x;  acc[2][1] += p4.z * va.y;
                acc[2][2] += p4.z * va.z;  acc[2][3] += p4.z * va.w;
                acc[2][4] += p4.z * vb4.x; acc[2][5] += p4.z * vb4.y;
                acc[2][6] += p4.z * vb4.z; acc[2][7] += p4.z * vb4.w;
                acc[3][0] += p4.w * va.x;  acc[3][1] += p4.w * va.y;
                acc[3][2] += p4.w * va.z;  acc[3][3] += p4.w * va.w;
                acc[3][4] += p4.w * vb4.x; acc[3][5] += p4.w * vb4.y;
                acc[3][6] += p4.w * vb4.z; acc[3][7] += p4.w * vb4.w;
            }
        }
        __syncthreads();
    }

    // finalize: divide by l, write attn[b][c][qbase+n]
    float i0 = 1.f / l_state[n_base + 0];
    float i1 = 1.f / l_state[n_base + 1];
    float i2 = 1.f / l_state[n_base + 2];
    float i3 = 1.f / l_state[n_base + 3];
    float* ab = attn + (size_t)b * CH * NN;
    #pragma unroll
    for (int cc = 0; cc < 8; ++cc) {
        int c = c_base + cc;
        *(float4*)&ab[(size_t)c * NN + qbase + n_base] =
            make_float4(acc[0][cc] * i0, acc[1][cc] * i1,
                        acc[2][cc] * i2, acc[3][cc] * i3);
    }
}

// ---------------------------------------------------------------------------
// K3: out = gamma * (Wo @ attn) + x.  grid (8, 8, 4), block 256.
// ---------------------------------------------------------------------------
__global__ __launch_bounds__(256) void out_kernel(
    const float* __restrict__ attn, const float* __restrict__ Wo,
    const float* __restrict__ x, const float* __restrict__ gamma,
    float* __restrict__ out)
{
    __shared__ float w_lds[CH][36];
    const int t = threadIdx.x;
    const int ntile = blockIdx.x;
    const int o_base = blockIdx.y * 32;
    const int b = blockIdx.z;

    #pragma unroll
    for (int i = 0; i < 32; ++i)
        w_lds[t][i] = Wo[(o_base + i) * CH + t];
    __syncthreads();

    const int n1 = ntile * 512 + t;
    const int n2 = n1 + 256;
    const float* ab = attn + (size_t)b * CH * NN;

    float acc1[32], acc2[32];
    #pragma unroll
    for (int o = 0; o < 32; ++o) { acc1[o] = 0.f; acc2[o] = 0.f; }

    for (int c = 0; c < CH; ++c) {
        float a1 = ab[c * NN + n1];
        float a2 = ab[c * NN + n2];
        #pragma unroll
        for (int o = 0; o < 32; ++o) {
            float w = w_lds[c][o];
            acc1[o] += w * a1;
            acc2[o] += w * a2;
        }
    }

    const float g = gamma[0];
    const float* xb = x + (size_t)b * CH * NN;
    float* ob = out + (size_t)b * CH * NN;
    #pragma unroll
    for (int o = 0; o < 32; ++o) {
        int c = o_base + o;
        ob[c * NN + n1] = g * acc1[o] + xb[c * NN + n1];
        ob[c * NN + n2] = g * acc2[o] + xb[c * NN + n2];
    }
}

// ---------------------------------------------------------------------------
extern "C" void kernel_launch(void* const* d_in, const int* in_sizes, int n_in,
                              void* d_out, int out_size, void* d_ws, size_t ws_size,
                              hipStream_t stream)
{
    const float* x     = (const float*)d_in[0];
    const float* Wq    = (const float*)d_in[1];
    const float* Wk    = (const float*)d_in[2];
    const float* Wv    = (const float*)d_in[3];
    const float* Wo    = (const float*)d_in[4];
    const float* gamma = (const float*)d_in[5];
    float* out = (float*)d_out;

    float* ws   = (float*)d_ws;
    float* q    = ws;                       // B*CR*N   = 524288
    float* k    = ws + 524288;              // B*CR*N   = 524288
    float* vt   = ws + 1048576;             // B*N*C    = 4194304
    float* attn = ws + 5242880;             // B*C*N    = 4194304
                                            // total 37.75 MB

    dim3 g1(8, 10, BATCH);
    qkv_kernel<<<g1, 256, 0, stream>>>(x, Wq, Wk, Wv, q, k, vt);

    dim3 g2(NN / QT, BATCH);
    attn_kernel<<<g2, 512, 0, stream>>>(q, k, vt, attn);

    dim3 g3(8, 8, BATCH);
    out_kernel<<<g3, 256, 0, stream>>>(attn, Wo, x, gamma, out);
}

// Round 2
// 373.486 us; speedup vs baseline: 2.4273x; 2.4273x over previous
//
#include <hip/hip_runtime.h>
#include <hip/hip_bf16.h>

#define BATCH 4
#define CH 256
#define CRD 32
#define NN 4096
#define QT 64
#define MT 32

typedef __bf16 bf16x8 __attribute__((ext_vector_type(8)));
typedef float floatx4 __attribute__((ext_vector_type(4)));
typedef float floatx16 __attribute__((ext_vector_type(16)));
typedef unsigned short ushort8v __attribute__((ext_vector_type(8)));

static __device__ __forceinline__ unsigned short f2bf(float f) {
    unsigned int u = __float_as_uint(f);
    u += 0x7fff + ((u >> 16) & 1);           // round-to-nearest-even
    return (unsigned short)(u >> 16);
}
static __device__ __forceinline__ float bf2f(unsigned short h) {
    return __uint_as_float((unsigned int)h << 16);
}

// ---------------------------------------------------------------------------
// K1: fused QKV conv. q (pre-scaled by 1/sqrt(32)), k: bf16 [B][N][CR].
// v: bf16 [B][C][N].  grid (8, 10, 4), block 256.
// ---------------------------------------------------------------------------
__global__ __launch_bounds__(256) void qkv_kernel(
    const float* __restrict__ x,
    const float* __restrict__ Wq, const float* __restrict__ Wk,
    const float* __restrict__ Wv,
    unsigned short* __restrict__ q, unsigned short* __restrict__ k,
    unsigned short* __restrict__ v_t)
{
    __shared__ float w_lds[CH][36];
    const int t = threadIdx.x;
    const int ntile = blockIdx.x;
    const int otile = blockIdx.y;
    const int b = blockIdx.z;

    const float* W;
    int o_base;
    if (otile == 0)      { W = Wq; o_base = 0; }
    else if (otile == 1) { W = Wk; o_base = 0; }
    else                 { W = Wv; o_base = (otile - 2) * 32; }

    #pragma unroll
    for (int i = 0; i < 32; ++i)
        w_lds[t][i] = W[(o_base + i) * CH + t];
    __syncthreads();

    const int n1 = ntile * 512 + t;
    const int n2 = n1 + 256;
    const float* xb = x + (size_t)b * CH * NN;

    float acc1[32], acc2[32];
    #pragma unroll
    for (int o = 0; o < 32; ++o) { acc1[o] = 0.f; acc2[o] = 0.f; }

    for (int c = 0; c < CH; ++c) {
        float xv1 = xb[c * NN + n1];
        float xv2 = xb[c * NN + n2];
        #pragma unroll
        for (int o = 0; o < 32; ++o) {
            float w = w_lds[c][o];
            acc1[o] += w * xv1;
            acc2[o] += w * xv2;
        }
    }

    if (otile <= 1) {
        const float sc = (otile == 0) ? 0.17677669529663687f : 1.0f;
        unsigned short* dst = (otile == 0 ? q : k) + (size_t)b * NN * CRD;
        #pragma unroll
        for (int v8 = 0; v8 < 4; ++v8) {
            ushort8v p1, p2;
            #pragma unroll
            for (int j = 0; j < 8; ++j) {
                p1[j] = f2bf(acc1[v8 * 8 + j] * sc);
                p2[j] = f2bf(acc2[v8 * 8 + j] * sc);
            }
            *(ushort8v*)(dst + (size_t)n1 * CRD + v8 * 8) = p1;
            *(ushort8v*)(dst + (size_t)n2 * CRD + v8 * 8) = p2;
        }
    } else {
        unsigned short* dst = v_t + (size_t)b * CH * NN;
        #pragma unroll
        for (int o = 0; o < 32; ++o) {
            dst[(size_t)(o_base + o) * NN + n1] = f2bf(acc1[o]);
            dst[(size_t)(o_base + o) * NN + n2] = f2bf(acc2[o]);
        }
    }
}

// ---------------------------------------------------------------------------
// K2: MFMA flash attention.  grid (N/QT=64, B=4), block 512 (8 waves).
// Scores: mfma 16x16x32 (K = CR = 32).  PV: mfma 32x32x16.
// attn written bf16 [B][C][N] (coalesced for K3) via LDS transpose.
// ---------------------------------------------------------------------------
__global__ __launch_bounds__(512) void attn_kernel(
    const unsigned short* __restrict__ qg, const unsigned short* __restrict__ kg,
    const unsigned short* __restrict__ vt, unsigned short* __restrict__ attn)
{
    __shared__ unsigned short q_lds[QT][40];    // [n][c]  (A-operand rows)
    __shared__ unsigned short k_lds[MT][40];    // [m][c]  (B^T rows)
    __shared__ unsigned short v_lds[CH][40];    // [c][m]  (B^T rows for PV)
    __shared__ float          s_lds[QT][36];    // fp32 scores [n][m]
    __shared__ unsigned short p_lds[QT][40];    // bf16 probs [n][m] (A rows)
    __shared__ float m_state[QT], l_state[QT], alpha_lds[QT];
    __shared__ float o_lds[CH][68];             // epilogue transpose [c][n]

    const int t = threadIdx.x;
    const int b = blockIdx.y;
    const int qbase = blockIdx.x * QT;
    const int w = t >> 6, l = t & 63;
    const int quad = l >> 4, l15 = l & 15;
    const int half = l >> 5, l31 = l & 31;

    const unsigned short* qb = qg + (size_t)b * NN * CRD;
    const unsigned short* kb = kg + (size_t)b * NN * CRD;
    const unsigned short* vb = vt + (size_t)b * CH * NN;

    // stage Q tile [64][32] bf16
    if (t < 256) {
        int n = t >> 2, seg = (t & 3) * 8;
        *(ushort8v*)&q_lds[n][seg] =
            *(const ushort8v*)(qb + (size_t)(qbase + n) * CRD + seg);
    }
    if (t < QT) { m_state[t] = -1e30f; l_state[t] = 0.f; }
    __syncthreads();

    // score tile ownership: wave w -> n-group a_n (16 rows), m-group g_m (16 keys)
    const int a_n = w & 3, g_m = w >> 2;
    bf16x8 qfrag = *(const bf16x8*)&q_lds[a_n * 16 + l15][quad * 8];

    // PV ownership: wave w -> n-group nb (32 rows), c-base c0 (64 channels)
    const int nb = w & 1, c0 = (w >> 1) * 64;
    floatx16 accA = {0.f}, accB = {0.f};
    #pragma unroll
    for (int i = 0; i < 16; ++i) { accA[i] = 0.f; accB[i] = 0.f; }

    for (int m0 = 0; m0 < NN; m0 += MT) {
        // ---- stage K tile [32][32] and V tile [256][32] ----
        if (t < 128) {
            int m = t >> 2, seg = (t & 3) * 8;
            *(ushort8v*)&k_lds[m][seg] =
                *(const ushort8v*)(kb + (size_t)(m0 + m) * CRD + seg);
        }
        {
            int c = t >> 1, sg = (t & 1) * 16;
            *(ushort8v*)&v_lds[c][sg] =
                *(const ushort8v*)(vb + (size_t)c * NN + m0 + sg);
            *(ushort8v*)&v_lds[c][sg + 8] =
                *(const ushort8v*)(vb + (size_t)c * NN + m0 + sg + 8);
        }
        __syncthreads();

        // ---- scores: one 16x16x32 MFMA per wave ----
        {
            bf16x8 kfrag = *(const bf16x8*)&k_lds[g_m * 16 + l15][quad * 8];
            floatx4 s4;
            #pragma unroll
            for (int r = 0; r < 4; ++r) s4[r] = 0.f;
            s4 = __builtin_amdgcn_mfma_f32_16x16x32_bf16(qfrag, kfrag, s4, 0, 0, 0);
            #pragma unroll
            for (int r = 0; r < 4; ++r)
                s_lds[a_n * 16 + quad * 4 + r][g_m * 16 + l15] = s4[r];
        }
        __syncthreads();

        // ---- online softmax: 8 threads per query ----
        {
            int qn = t >> 3, mo = t & 7;
            floatx4 sv = *(floatx4*)&s_lds[qn][mo * 4];
            float smax = fmaxf(fmaxf(sv[0], sv[1]), fmaxf(sv[2], sv[3]));
            smax = fmaxf(smax, __shfl_xor(smax, 1));
            smax = fmaxf(smax, __shfl_xor(smax, 2));
            smax = fmaxf(smax, __shfl_xor(smax, 4));
            float mold = m_state[qn];
            float mnew = fmaxf(mold, smax);
            float p0 = __expf(sv[0] - mnew), p1 = __expf(sv[1] - mnew);
            float p2 = __expf(sv[2] - mnew), p3 = __expf(sv[3] - mnew);
            float psum = p0 + p1 + p2 + p3;
            psum += __shfl_xor(psum, 1);
            psum += __shfl_xor(psum, 2);
            psum += __shfl_xor(psum, 4);
            p_lds[qn][mo * 4 + 0] = f2bf(p0);
            p_lds[qn][mo * 4 + 1] = f2bf(p1);
            p_lds[qn][mo * 4 + 2] = f2bf(p2);
            p_lds[qn][mo * 4 + 3] = f2bf(p3);
            if (mo == 0) {
                float al = __expf(mold - mnew);
                m_state[qn] = mnew;
                alpha_lds[qn] = al;
                l_state[qn] = l_state[qn] * al + psum;
            }
        }
        __syncthreads();

        // ---- PV: rescale accumulators, then 4x mfma 32x32x16 per wave ----
        {
            const int rbase = nb * 32 + 4 * half;
            floatx4 al0 = *(floatx4*)&alpha_lds[rbase];
            floatx4 al1 = *(floatx4*)&alpha_lds[rbase + 8];
            floatx4 al2 = *(floatx4*)&alpha_lds[rbase + 16];
            floatx4 al3 = *(floatx4*)&alpha_lds[rbase + 24];
            #pragma unroll
            for (int i = 0; i < 4; ++i) {
                accA[i]      *= al0[i]; accB[i]      *= al0[i];
                accA[i + 4]  *= al1[i]; accB[i + 4]  *= al1[i];
                accA[i + 8]  *= al2[i]; accB[i + 8]  *= al2[i];
                accA[i + 12] *= al3[i]; accB[i + 12] *= al3[i];
            }
            #pragma unroll
            for (int kh = 0; kh < 2; ++kh) {
                bf16x8 pa = *(const bf16x8*)&p_lds[nb * 32 + l31][kh * 16 + half * 8];
                bf16x8 v0 = *(const bf16x8*)&v_lds[c0 + l31][kh * 16 + half * 8];
                bf16x8 v1 = *(const bf16x8*)&v_lds[c0 + 32 + l31][kh * 16 + half * 8];
                accA = __builtin_amdgcn_mfma_f32_32x32x16_bf16(pa, v0, accA, 0, 0, 0);
                accB = __builtin_amdgcn_mfma_f32_32x32x16_bf16(pa, v1, accB, 0, 0, 0);
            }
        }
        __syncthreads();
    }

    // ---- epilogue: divide by l, transpose through LDS, store bf16 [c][n] ----
    {
        const int rbase = nb * 32 + 4 * half;
        floatx4 li0 = *(floatx4*)&l_state[rbase];
        floatx4 li1 = *(floatx4*)&l_state[rbase + 8];
        floatx4 li2 = *(floatx4*)&l_state[rbase + 16];
        floatx4 li3 = *(floatx4*)&l_state[rbase + 24];
        floatx4 inv0, inv1, inv2, inv3;
        #pragma unroll
        for (int i = 0; i < 4; ++i) {
            inv0[i] = 1.f / li0[i]; inv1[i] = 1.f / li1[i];
            inv2[i] = 1.f / li2[i]; inv3[i] = 1.f / li3[i];
        }
        #pragma unroll
        for (int rg = 0; rg < 4; ++rg) {
            floatx4 inv = (rg == 0) ? inv0 : (rg == 1) ? inv1 : (rg == 2) ? inv2 : inv3;
            floatx4 oA, oB;
            #pragma unroll
            for (int rr = 0; rr < 4; ++rr) {
                oA[rr] = accA[rg * 4 + rr] * inv[rr];
                oB[rr] = accB[rg * 4 + rr] * inv[rr];
            }
            *(floatx4*)&o_lds[c0 + l31][rbase + 8 * rg] = oA;
            *(floatx4*)&o_lds[c0 + 32 + l31][rbase + 8 * rg] = oB;
        }
    }
    __syncthreads();
    {
        unsigned short* ab = attn + (size_t)b * CH * NN;
        int c = t >> 1, nh = (t & 1) * 32;
        #pragma unroll
        for (int j = 0; j < 4; ++j) {
            ushort8v pk;
            #pragma unroll
            for (int i = 0; i < 8; ++i)
                pk[i] = f2bf(o_lds[c][nh + j * 8 + i]);
            *(ushort8v*)(ab + (size_t)c * NN + qbase + nh + j * 8) = pk;
        }
    }
}

// ---------------------------------------------------------------------------
// K3: out = gamma * (Wo @ attn) + x.  attn is bf16 [B][C][N].
// grid (8, 8, 4), block 256.
// ---------------------------------------------------------------------------
__global__ __launch_bounds__(256) void out_kernel(
    const unsigned short* __restrict__ attn, const float* __restrict__ Wo,
    const float* __restrict__ x, const float* __restrict__ gamma,
    float* __restrict__ out)
{
    __shared__ float w_lds[CH][36];
    const int t = threadIdx.x;
    const int ntile = blockIdx.x;
    const int o_base = blockIdx.y * 32;
    const int b = blockIdx.z;

    #pragma unroll
    for (int i = 0; i < 32; ++i)
        w_lds[t][i] = Wo[(o_base + i) * CH + t];
    __syncthreads();

    const int n1 = ntile * 512 + t;
    const int n2 = n1 + 256;
    const unsigned short* ab = attn + (size_t)b * CH * NN;

    float acc1[32], acc2[32];
    #pragma unroll
    for (int o = 0; o < 32; ++o) { acc1[o] = 0.f; acc2[o] = 0.f; }

    for (int c = 0; c < CH; ++c) {
        float a1 = bf2f(ab[c * NN + n1]);
        float a2 = bf2f(ab[c * NN + n2]);
        #pragma unroll
        for (int o = 0; o < 32; ++o) {
            float w = w_lds[c][o];
            acc1[o] += w * a1;
            acc2[o] += w * a2;
        }
    }

    const float g = gamma[0];
    const float* xb = x + (size_t)b * CH * NN;
    float* ob = out + (size_t)b * CH * NN;
    #pragma unroll
    for (int o = 0; o < 32; ++o) {
        int c = o_base + o;
        ob[c * NN + n1] = g * acc1[o] + xb[c * NN + n1];
        ob[c * NN + n2] = g * acc2[o] + xb[c * NN + n2];
    }
}

// ---------------------------------------------------------------------------
extern "C" void kernel_launch(void* const* d_in, const int* in_sizes, int n_in,
                              void* d_out, int out_size, void* d_ws, size_t ws_size,
                              hipStream_t stream)
{
    const float* x     = (const float*)d_in[0];
    const float* Wq    = (const float*)d_in[1];
    const float* Wk    = (const float*)d_in[2];
    const float* Wv    = (const float*)d_in[3];
    const float* Wo    = (const float*)d_in[4];
    const float* gamma = (const float*)d_in[5];
    float* out = (float*)d_out;

    char* wsb = (char*)d_ws;
    unsigned short* q    = (unsigned short*)(wsb);                    // 1 MB
    unsigned short* k    = (unsigned short*)(wsb + (1u << 20));       // 1 MB
    unsigned short* vt   = (unsigned short*)(wsb + (2u << 20));       // 8 MB
    unsigned short* attn = (unsigned short*)(wsb + (10u << 20));      // 8 MB

    dim3 g1(8, 10, BATCH);
    qkv_kernel<<<g1, 256, 0, stream>>>(x, Wq, Wk, Wv, q, k, vt);

    dim3 g2(NN / QT, BATCH);
    attn_kernel<<<g2, 512, 0, stream>>>(q, k, vt, attn);

    dim3 g3(8, 8, BATCH);
    out_kernel<<<g3, 256, 0, stream>>>(attn, Wo, x, gamma, out);
}